// Round 6
// baseline (642.472 us; speedup 1.0000x reference)
//
#include <hip/hip_runtime.h>
#include <math.h>

#define Bq 128
#define Nn 8
#define LQ 32
#define LD 256
#define DD 128
#define EPSN 1e-12f
#define NEGV (-9999.0f)

// ---------------- Kernel 1: normalize q rows over D ----------------
__global__ __launch_bounds__(256) void qnorm_k(const float* __restrict__ q,
                                               float* __restrict__ qn) {
    int row  = blockIdx.x * 4 + (threadIdx.x >> 6);   // 4096 rows total
    int lane = threadIdx.x & 63;
    size_t base = (size_t)row * DD + lane * 2;
    float2 v = *reinterpret_cast<const float2*>(q + base);
    float ss = v.x * v.x + v.y * v.y;
#pragma unroll
    for (int o = 32; o; o >>= 1) ss += __shfl_xor(ss, o);
    float inv = 1.0f / fmaxf(sqrtf(ss), EPSN);
    float2 o2; o2.x = v.x * inv; o2.y = v.y * inv;
    *reinterpret_cast<float2*>(qn + base) = o2;
}

// ---------------- Kernel 2: MaxSim scores ----------------
// grid = Nn*Bq blocks x 512 threads; block = one (n,b), both tensors.
// Thread t owns d-row (t>>1) of tensor (t&1) (round 5: 52 VGPR base, clean
// 200MB fetch). NEW: register ping-pong prefetch at 128B granularity --
// loads for chunk c+1 issue BEFORE computing chunk c, so ~128B/wave stays
// in flight under ~1024 cyc of compute (hides ~900 cyc HBM latency; round 5
// measured 1.45 TB/s = Little's-law limit at 64B-blocking depth 0).
__global__ __launch_bounds__(512) void maxsim_k(const float* __restrict__ d_cq,
                                                const float* __restrict__ d_orig,
                                                const int* __restrict__ mask,
                                                const float* __restrict__ qn,
                                                float* __restrict__ scores) {
    __shared__ float q_lds[LQ][DD];   // 16 KB
    __shared__ float wm[8][64];       // 2 KB

    int nb = blockIdx.x;              // n*Bq + b
    int b  = nb & 127;
    int n  = nb >> 7;
    int tid = threadIdx.x;

    {   // stage q[b] -> LDS, coalesced float4 (512 thr x 2 = 1024 float4)
        const float4* src = reinterpret_cast<const float4*>(qn + (size_t)b * LQ * DD);
        float4* dst = reinterpret_cast<float4*>(&q_lds[0][0]);
        dst[tid]       = src[tid];
        dst[tid + 512] = src[tid + 512];
    }
    __syncthreads();

    int row    = tid >> 1;
    int parity = tid & 1;             // 0 = cq (student), 1 = orig (teacher)
    const float* dten = parity ? d_orig : d_cq;
    const float4* p = reinterpret_cast<const float4*>(
        dten + (size_t)nb * LD * DD + (size_t)row * DD);

    float acc[LQ];
#pragma unroll
    for (int i = 0; i < LQ; ++i) acc[i] = 0.0f;
    float ssq = 0.0f;

#define SB __builtin_amdgcn_sched_barrier(0)

#define QSTEP(AV, QOFF)                                                        \
    {                                                                          \
        ssq += AV.x*AV.x + AV.y*AV.y + AV.z*AV.z + AV.w*AV.w;                  \
        _Pragma("unroll")                                                      \
        for (int lq = 0; lq < LQ; ++lq) {                                      \
            float4 qv = *reinterpret_cast<const float4*>(                      \
                &q_lds[lq][(QOFF)]);  /* wave-uniform -> broadcast */          \
            acc[lq] += qv.x*AV.x + qv.y*AV.y + qv.z*AV.z + qv.w*AV.w;          \
        }                                                                      \
    }

#define LOADC(X, idx)                                                          \
    {                                                                          \
        const float4* pp = p + (idx) * 8;                                      \
        X##0 = pp[0]; X##1 = pp[1]; X##2 = pp[2]; X##3 = pp[3];                \
        X##4 = pp[4]; X##5 = pp[5]; X##6 = pp[6]; X##7 = pp[7];                \
    }

#define COMPC(X, cb)                                                           \
    QSTEP(X##0, (cb) * 32 + 0);  SB;                                           \
    QSTEP(X##1, (cb) * 32 + 4);  SB;                                           \
    QSTEP(X##2, (cb) * 32 + 8);  SB;                                           \
    QSTEP(X##3, (cb) * 32 + 12); SB;                                           \
    QSTEP(X##4, (cb) * 32 + 16); SB;                                           \
    QSTEP(X##5, (cb) * 32 + 20); SB;                                           \
    QSTEP(X##6, (cb) * 32 + 24); SB;                                           \
    QSTEP(X##7, (cb) * 32 + 28); SB;

    float4 A0, A1, A2, A3, A4, A5, A6, A7;
    float4 B0, B1, B2, B3, B4, B5, B6, B7;

    LOADC(A, 0); SB;
#pragma unroll 1
    for (int cc = 0; cc < 2; ++cc) {        // 2 x (two 128B chunks)
        int c0 = cc * 2;
        LOADC(B, c0 + 1); SB;               // prefetch next chunk
        COMPC(A, c0);                        // compute current (B in flight)
        int c2 = (c0 + 2 < 3) ? c0 + 2 : 3;  // clamped (last is L1-hit refetch)
        LOADC(A, c2); SB;
        COMPC(B, c0 + 1);
    }
#undef QSTEP
#undef LOADC
#undef COMPC

    int mk = mask[(size_t)nb * LD + row];   // same mask for both tensors
    float inv = 1.0f / fmaxf(sqrtf(ssq), EPSN);

    int lane = tid & 63, wv = tid >> 6;
    float sel = NEGV;
#pragma unroll
    for (int lq = 0; lq < LQ; ++lq) {
        float s = mk ? acc[lq] * inv : NEGV;
        // reduce over the wave's 32 rows of this parity (bits 1..5)
#pragma unroll
        for (int o = 2; o <= 32; o <<= 1) s = fmaxf(s, __shfl_xor(s, o));
        if ((lane >> 1) == lq) sel = s;   // lane 2*lq+parity keeps (lq, tensor)
    }
    wm[wv][lane] = sel;
    __syncthreads();

    if (tid < 64) {
        float v = wm[0][tid];
#pragma unroll
        for (int w = 1; w < 8; ++w) v = fmaxf(v, wm[w][tid]);
        // sum over lq within parity class
#pragma unroll
        for (int o = 2; o <= 32; o <<= 1) v += __shfl_xor(v, o);
        if (tid < 2)
            scores[tid * (Bq * Nn) + b * Nn + n] = v;
    }
}

// ---------------- Kernel 3: log_softmax + KL ----------------
__global__ void loss_k(const float* __restrict__ scores, float* __restrict__ out) {
    int tid = threadIdx.x;   // 128 threads, one per b
    const float* s = scores + tid * Nn;            // student (cq)
    const float* t = scores + Bq * Nn + tid * Nn;  // teacher (orig)
    float sv[Nn], tv[Nn];
#pragma unroll
    for (int n = 0; n < Nn; ++n) { sv[n] = s[n]; tv[n] = t[n]; }
    float ms = sv[0], mt = tv[0];
#pragma unroll
    for (int n = 1; n < Nn; ++n) { ms = fmaxf(ms, sv[n]); mt = fmaxf(mt, tv[n]); }
    float es = 0.0f, et = 0.0f;
#pragma unroll
    for (int n = 0; n < Nn; ++n) { es += expf(sv[n] - ms); et += expf(tv[n] - mt); }
    float lses = ms + logf(es);
    float lset = mt + logf(et);
    double kl = 0.0;
#pragma unroll
    for (int n = 0; n < Nn; ++n) {
        float lt = tv[n] - lset;
        float ls = sv[n] - lses;
        kl += (double)expf(lt) * ((double)lt - (double)ls);
    }
#pragma unroll
    for (int o = 32; o; o >>= 1) kl += __shfl_xor(kl, o);
    __shared__ double part[2];
    if ((tid & 63) == 0) part[tid >> 6] = kl;
    __syncthreads();
    if (tid == 0) out[0] = (float)((part[0] + part[1]) / (double)Bq);
}

extern "C" void kernel_launch(void* const* d_in, const int* in_sizes, int n_in,
                              void* d_out, int out_size, void* d_ws, size_t ws_size,
                              hipStream_t stream) {
    const float* q     = (const float*)d_in[0];
    const float* dcq   = (const float*)d_in[1];
    const float* dorig = (const float*)d_in[2];
    const int*   mask  = (const int*)d_in[3];
    // labels (d_in[4]) unused by the reference loss path

    float* qn     = (float*)d_ws;                      // [B*LQ*DD] = 2MB
    float* scores = qn + (size_t)Bq * LQ * DD;         // [2][B][N] = 8KB

    qnorm_k<<<(Bq * LQ) / 4, 256, 0, stream>>>(q, qn);
    maxsim_k<<<Nn * Bq, 512, 0, stream>>>(dcq, dorig, mask, qn, scores);
    loss_k<<<1, 128, 0, stream>>>(scores, (float*)d_out);
}

// Round 7
// 72.597 us; speedup vs baseline: 8.8498x; 8.8498x over previous
//
#include <hip/hip_runtime.h>
#include <math.h>

#define Bq 128
#define Nn 8
#define LQ 32
#define LD 256
#define DD 128
#define EPSN 1e-12f
#define NEGV (-9999.0f)

typedef __attribute__((ext_vector_type(8))) short short8v;
typedef __attribute__((ext_vector_type(4))) int   int4v;
typedef __attribute__((ext_vector_type(4))) float f32x4;

__device__ __forceinline__ unsigned bf16_rne_hibits(float x) {
    // returns (round-to-nearest-even bf16 of x) << 16, as f32 bit pattern
    unsigned u = __float_as_uint(x);
    return (u + 0x7FFFu + ((u >> 16) & 1u)) & 0xFFFF0000u;
}

// ---------------- Kernel 1: normalize q rows, emit bf16 hi/lo planes -------
__global__ __launch_bounds__(256) void qnorm_k(const float* __restrict__ q,
                                               unsigned short* __restrict__ qh,
                                               unsigned short* __restrict__ ql) {
    int row  = blockIdx.x * 4 + (threadIdx.x >> 6);   // 4096 rows = [B][LQ]
    int lane = threadIdx.x & 63;
    size_t base = (size_t)row * DD + lane * 2;
    float2 v = *reinterpret_cast<const float2*>(q + base);
    float ss = v.x * v.x + v.y * v.y;
#pragma unroll
    for (int o = 32; o; o >>= 1) ss += __shfl_xor(ss, o);
    float inv = 1.0f / fmaxf(sqrtf(ss), EPSN);
    float x0 = v.x * inv, x1 = v.y * inv;
    unsigned h0 = bf16_rne_hibits(x0), h1 = bf16_rne_hibits(x1);
    float l0 = x0 - __uint_as_float(h0);
    float l1 = x1 - __uint_as_float(h1);
    unsigned g0 = bf16_rne_hibits(l0), g1 = bf16_rne_hibits(l1);
    *reinterpret_cast<unsigned*>(qh + base) = (h0 >> 16) | h1;
    *reinterpret_cast<unsigned*>(ql + base) = (g0 >> 16) | g1;
}

// ---------------- Kernel 2: MaxSim via MFMA ----------------
// grid = 2*Nn*Bq blocks x 256 thr. Block = (tensor, n, b). Wave w owns d-rows
// [w*64, w*64+64). Per 16-row N-tile: C[32 lq x 16 rows] = Q * Drows^T via
// mfma_f32_16x16x32_bf16, hi/lo split (3 terms). d is read ONCE, straight
// global->VGPR->cvt->MFMA (no LDS, no reuse needed: B-frags are disjoint).
// Q hi/lo planes read as A-frags from global (16KB/b, L1/L2-resident).
__global__ __launch_bounds__(256) void maxsim_k(const float* __restrict__ d_cq,
                                                const float* __restrict__ d_orig,
                                                const int* __restrict__ mask,
                                                const unsigned short* __restrict__ qh,
                                                const unsigned short* __restrict__ ql,
                                                float* __restrict__ scores) {
    __shared__ float wm[4][32];

    int bid = blockIdx.x;             // [0, 2048)
    int tau = bid >> 10;              // 0 = cq (student), 1 = orig (teacher)
    int nb  = bid & 1023;             // n*Bq + b
    int b   = nb & 127;
    int n   = nb >> 7;

    int tid  = threadIdx.x;
    int w    = tid >> 6;              // wave id: d-rows [w*64, w*64+64)
    int lane = tid & 63;
    int r    = lane & 15;             // B-frag col / C-frag col (local d-row)
    int g    = lane >> 4;             // k-group (8 elems each)

    const float* dbase = (tau ? d_orig : d_cq) + (size_t)nb * (LD * DD);

    // A-fragment row pointers (ushorts), fixed across nt: lq = r and 16+r
    const unsigned short* qh_r  = qh + ((size_t)b * LQ + r) * DD + g * 8;
    const unsigned short* ql_r  = ql + ((size_t)b * LQ + r) * DD + g * 8;
    const unsigned short* qh_r2 = qh_r + 16 * DD;
    const unsigned short* ql_r2 = ql_r + 16 * DD;

    f32x4 rm0 = {NEGV, NEGV, NEGV, NEGV};
    f32x4 rm1 = {NEGV, NEGV, NEGV, NEGV};

#define SB __builtin_amdgcn_sched_barrier(0)

#define CVT2(W, X0, X1)                                                        \
    { unsigned h0 = bf16_rne_hibits(X0), h1 = bf16_rne_hibits(X1);             \
      float lf0 = (X0) - __uint_as_float(h0);                                  \
      float lf1 = (X1) - __uint_as_float(h1);                                  \
      dhw[W] = (int)((h0 >> 16) | h1);                                         \
      dlw[W] = (int)((bf16_rne_hibits(lf0) >> 16) | bf16_rne_hibits(lf1));     \
      ssq += (X0)*(X0) + (X1)*(X1); }

#define KSTEP(C0, C1, N0, N1, KS, KSN)                                         \
    {                                                                          \
        N0 = *reinterpret_cast<const float4*>(prow + (KSN) * 32);              \
        N1 = *reinterpret_cast<const float4*>(prow + (KSN) * 32 + 4);          \
        short8v a0h = *reinterpret_cast<const short8v*>(qh_r  + (KS) * 32);    \
        short8v a0l = *reinterpret_cast<const short8v*>(ql_r  + (KS) * 32);    \
        short8v a1h = *reinterpret_cast<const short8v*>(qh_r2 + (KS) * 32);    \
        short8v a1l = *reinterpret_cast<const short8v*>(ql_r2 + (KS) * 32);    \
        int4v dhw, dlw;                                                        \
        CVT2(0, C0.x, C0.y) CVT2(1, C0.z, C0.w)                                \
        CVT2(2, C1.x, C1.y) CVT2(3, C1.z, C1.w)                                \
        short8v dh = __builtin_bit_cast(short8v, dhw);                         \
        short8v dl = __builtin_bit_cast(short8v, dlw);                         \
        c0 = __builtin_amdgcn_mfma_f32_16x16x32_bf16(a0h, dh, c0, 0, 0, 0);    \
        c1 = __builtin_amdgcn_mfma_f32_16x16x32_bf16(a1h, dh, c1, 0, 0, 0);    \
        c0 = __builtin_amdgcn_mfma_f32_16x16x32_bf16(a0h, dl, c0, 0, 0, 0);    \
        c1 = __builtin_amdgcn_mfma_f32_16x16x32_bf16(a1h, dl, c1, 0, 0, 0);    \
        c0 = __builtin_amdgcn_mfma_f32_16x16x32_bf16(a0l, dh, c0, 0, 0, 0);    \
        c1 = __builtin_amdgcn_mfma_f32_16x16x32_bf16(a1l, dh, c1, 0, 0, 0);    \
    }

#pragma unroll 1
    for (int nt = 0; nt < 4; ++nt) {
        int drow = w * 64 + nt * 16 + r;          // this lane's d-row (B col)
        const float* prow = dbase + (size_t)drow * DD + g * 8;

        f32x4 c0 = {0.f, 0.f, 0.f, 0.f};
        f32x4 c1 = {0.f, 0.f, 0.f, 0.f};
        float ssq = 0.0f;

        float4 p0 = *reinterpret_cast<const float4*>(prow);
        float4 p1 = *reinterpret_cast<const float4*>(prow + 4);
        float4 q0, q1;
        KSTEP(p0, p1, q0, q1, 0, 1); SB;
        KSTEP(q0, q1, p0, p1, 1, 2); SB;
        KSTEP(p0, p1, q0, q1, 2, 3); SB;
        KSTEP(q0, q1, p0, p1, 3, 3); SB;   // last prefetch is dead (DCE/L1)

        // full row ssq: lane covers k = ks*32 + g*8 + e; combine 4 g-lanes
        ssq += __shfl_xor(ssq, 16);
        ssq += __shfl_xor(ssq, 32);
        int   mk  = mask[(size_t)nb * LD + drow];
        float inv = 1.0f / fmaxf(sqrtf(ssq), EPSN);

        // C layout: col = lane&15 = local d-row; row(lq) = g*4 + i (+16 for c1)
#pragma unroll
        for (int i = 0; i < 4; ++i) {
            float s0 = mk ? c0[i] * inv : NEGV;
            float s1 = mk ? c1[i] * inv : NEGV;
            rm0[i] = fmaxf(rm0[i], s0);
            rm1[i] = fmaxf(rm1[i], s1);
        }
    }
#undef KSTEP
#undef CVT2

    // max over the wave's 64 d-rows: reduce across the 16 cols (lane&15)
#pragma unroll
    for (int i = 0; i < 4; ++i) {
#pragma unroll
        for (int o = 1; o <= 8; o <<= 1) {
            rm0[i] = fmaxf(rm0[i], __shfl_xor(rm0[i], o));
            rm1[i] = fmaxf(rm1[i], __shfl_xor(rm1[i], o));
        }
    }
    if (r == 0) {
#pragma unroll
        for (int i = 0; i < 4; ++i) {
            wm[w][g * 4 + i]      = rm0[i];
            wm[w][16 + g * 4 + i] = rm1[i];
        }
    }
    __syncthreads();

    if (tid < 32) {   // lane = lq
        float v = fmaxf(fmaxf(wm[0][tid], wm[1][tid]),
                        fmaxf(wm[2][tid], wm[3][tid]));
#pragma unroll
        for (int o = 1; o <= 16; o <<= 1) v += __shfl_xor(v, o);
        if (tid == 0)
            scores[tau * (Bq * Nn) + b * Nn + n] = v;
    }
}

// ---------------- Kernel 3: log_softmax + KL ----------------
__global__ void loss_k(const float* __restrict__ scores, float* __restrict__ out) {
    int tid = threadIdx.x;   // 128 threads, one per b
    const float* s = scores + tid * Nn;            // student (cq)
    const float* t = scores + Bq * Nn + tid * Nn;  // teacher (orig)
    float sv[Nn], tv[Nn];
#pragma unroll
    for (int n = 0; n < Nn; ++n) { sv[n] = s[n]; tv[n] = t[n]; }
    float ms = sv[0], mt = tv[0];
#pragma unroll
    for (int n = 1; n < Nn; ++n) { ms = fmaxf(ms, sv[n]); mt = fmaxf(mt, tv[n]); }
    float es = 0.0f, et = 0.0f;
#pragma unroll
    for (int n = 0; n < Nn; ++n) { es += expf(sv[n] - ms); et += expf(tv[n] - mt); }
    float lses = ms + logf(es);
    float lset = mt + logf(et);
    double kl = 0.0;
#pragma unroll
    for (int n = 0; n < Nn; ++n) {
        float lt = tv[n] - lset;
        float ls = sv[n] - lses;
        kl += (double)expf(lt) * ((double)lt - (double)ls);
    }
#pragma unroll
    for (int o = 32; o; o >>= 1) kl += __shfl_xor(kl, o);
    __shared__ double part[2];
    if ((tid & 63) == 0) part[tid >> 6] = kl;
    __syncthreads();
    if (tid == 0) out[0] = (float)((part[0] + part[1]) / (double)Bq);
}

extern "C" void kernel_launch(void* const* d_in, const int* in_sizes, int n_in,
                              void* d_out, int out_size, void* d_ws, size_t ws_size,
                              hipStream_t stream) {
    const float* q     = (const float*)d_in[0];
    const float* dcq   = (const float*)d_in[1];
    const float* dorig = (const float*)d_in[2];
    const int*   mask  = (const int*)d_in[3];
    // labels (d_in[4]) unused by the reference loss path

    unsigned short* qh = (unsigned short*)d_ws;                  // [B][32][128] bf16-hi, 1MB
    unsigned short* ql = qh + (size_t)Bq * LQ * DD;              // bf16-lo, 1MB
    float* scores      = (float*)(ql + (size_t)Bq * LQ * DD);    // [2][B][N], 8KB

    qnorm_k<<<(Bq * LQ) / 4, 256, 0, stream>>>(q, qh, ql);
    maxsim_k<<<2 * Nn * Bq, 256, 0, stream>>>(dcq, dorig, mask, qh, ql, scores);
    loss_k<<<1, 128, 0, stream>>>(scores, (float*)d_out);
}